// Round 14
// baseline (221.658 us; speedup 1.0000x reference)
//
#include <hip/hip_runtime.h>
#include <hip/hip_fp16.h>

#define N_Q   16384
#define C_DIM 128
#define S_CAM 6
#define M_VAL 1400   // 28*50
#define D_Z   8
#define HF    28
#define WF    50
#define QT    128    // queries per gather block
#define CSTR  48     // LDS camera-slice row stride in bytes (32B data + 16B pad)

typedef float f32x2 __attribute__((ext_vector_type(2)));

__device__ __forceinline__ bool mask_any(const unsigned char* __restrict__ mask,
                                         int mflag, size_t mbase){
  if(mflag==0){
    int any=0;
    #pragma unroll
    for(int d=0;d<D_Z;d++) any |= mask[mbase+d];
    return any!=0;
  } else if(mflag==1){
    const int* mp = (const int*)mask;  int any=0;
    #pragma unroll
    for(int d=0;d<D_Z;d++) any |= mp[mbase+d];
    return any!=0;
  } else {
    const long long* mp = (const long long*)mask;  long long any=0;
    #pragma unroll
    for(int d=0;d<D_Z;d++) any |= mp[mbase+d];
    return any!=0;
  }
}

// fp8x16 corner accumulate: 16 channels from one uint4, weight wgt.
__device__ __forceinline__ void corner_acc(const uint4 cv, const float wgt,
                                           float* __restrict__ acc){
  const unsigned dw[4] = {cv.x, cv.y, cv.z, cv.w};
  #pragma unroll
  for(int j=0;j<4;j++){
    const f32x2 lo = __builtin_amdgcn_cvt_pk_f32_fp8(dw[j], false);
    const f32x2 hi = __builtin_amdgcn_cvt_pk_f32_fp8(dw[j], true);
    acc[j*4+0] += wgt*lo[0];  acc[j*4+1] += wgt*lo[1];
    acc[j*4+2] += wgt*hi[0];  acc[j*4+3] += wgt*hi[1];
  }
}

// ---------------------------------------------------------------------------
// A: v = value @ Wv + bv -> FP8 e4m3 workspace (proven R13 shape).
// Block 0 piggybacks the bev_mask upload-format sniff (0=u8,1=i32,2=i64).
// ---------------------------------------------------------------------------
__global__ __launch_bounds__(256)
void value_proj_kernel(const float* __restrict__ value,
                       const float* __restrict__ Wv,
                       const float* __restrict__ bv,
                       unsigned char* __restrict__ v8,
                       const unsigned char* __restrict__ mask,
                       int* __restrict__ flag){
  __shared__ float tile[8][C_DIM];
  __shared__ int s_cntA, s_cntB;
  const int tid = threadIdx.x;
  const int col = tid & 127;
  const int rh  = tid >> 7;
  const int r0  = blockIdx.x * 8;
  if(blockIdx.x==0 && tid==0){ s_cntA=0; s_cntB=0; }
  {
    const float4* src = (const float4*)(value + (size_t)r0*C_DIM);
    ((float4*)&tile[0][0])[tid] = src[tid];
  }
  __syncthreads();
  float acc[4];
  const float bias = bv[col];
  #pragma unroll
  for(int r=0;r<4;r++) acc[r]=bias;
  for(int k=0;k<C_DIM;k+=4){
    const float w0 = Wv[(k+0)*C_DIM + col];
    const float w1 = Wv[(k+1)*C_DIM + col];
    const float w2 = Wv[(k+2)*C_DIM + col];
    const float w3 = Wv[(k+3)*C_DIM + col];
    #pragma unroll
    for(int r=0;r<4;r++){
      const float4 t = *(const float4*)&tile[rh*4+r][k];
      acc[r] += t.x*w0 + t.y*w1 + t.z*w2 + t.w*w3;
    }
  }
  #pragma unroll
  for(int r=0;r<4;r++){
    const int pk = __builtin_amdgcn_cvt_pk_fp8_f32(acc[r], acc[r], 0, false);
    v8[(size_t)(r0+rh*4+r)*C_DIM + col] = (unsigned char)(pk & 0xff);
  }
  if(blockIdx.x==0){
    int a=0, b=0;
    for(int i=tid;i<1024;i+=256){
      const unsigned char v = mask[i];
      if(((i&3)!=0) && v) a=1;
      if(((i&7)==4) && v) b=1;
    }
    if(a) atomicOr(&s_cntA,1);
    if(b) atomicOr(&s_cntB,1);
    __syncthreads();
    if(tid==0) flag[0] = s_cntA ? 0 : (s_cntB ? 1 : 2);
  }
}

// ---------------------------------------------------------------------------
// B: per-(query-tile, head) block. q-proj for the head's 24 cols (no
// redundancy), then per camera: stage the 44.8KB fp8 slice into LDS and
// gather via ds_read_b128 — zero L1 misses in the gather (R10-R13 showed an
// L1-miss-concurrency wall: bytes/requests/waves changes were all ~neutral).
// Slots written fp16 to workspace; out-proj in kernel C.
// ---------------------------------------------------------------------------
__global__ __launch_bounds__(256)
void gather_kernel(const unsigned char* __restrict__ v8,
                   const float* __restrict__ query,
                   const float* __restrict__ query_pos,
                   const float* __restrict__ Wo, const float* __restrict__ bo,
                   const float* __restrict__ Wa, const float* __restrict__ ba,
                   const float* __restrict__ ref,
                   const unsigned char* __restrict__ mask,
                   const int* __restrict__ flag,
                   unsigned short* __restrict__ slots16){
  __shared__ union {
    struct {                                  // proj phase (21.5 KB)
      float qsL[32][132];                     // 132: conflict-free broadcast rows
      float logitsL[128][9];
    } pre;
    unsigned char cam[M_VAL*CSTR];            // cam phase (67.2 KB)
  } U;
  __shared__ float offsL[128][17];            // stride 17: gcd(17,32)=1
  __shared__ float attnL[128][8];
  __shared__ float cinvL[128];
  __shared__ unsigned char activL[128][8];

  const int tid = threadIdx.x;
  const int h   = blockIdx.x & 3;
  const int n0  = (blockIdx.x >> 2) * QT;
  const int mflag = flag[0];

  // ---- 1) q-proj, head slice only: 4 chunks of 32 queries ----
  const int pq = tid >> 3;                    // 0..31
  const int pj = tid & 7;                     // 0..7: off cols 2pj,2pj+1; logit pj
  for(int c=0;c<4;c++){
    {
      const float4* qa = (const float4*)(query     + (size_t)(n0 + c*32)*C_DIM);
      const float4* qb = (const float4*)(query_pos + (size_t)(n0 + c*32)*C_DIM);
      #pragma unroll
      for(int i=0;i<4;i++){
        const int idx = tid + 256*i;          // 1024 float4 = 32 rows x 128 f
        const int r = idx >> 5, cc = idx & 31;
        float4 A = qa[idx], B = qb[idx];
        *(float4*)&U.pre.qsL[r][cc*4] = make_float4(A.x+B.x, A.y+B.y, A.z+B.z, A.w+B.w);
      }
    }
    __syncthreads();
    {
      float ao0 = bo[h*16 + pj*2], ao1 = bo[h*16 + pj*2 + 1];
      float aa  = ba[h*8 + pj];
      for(int k=0;k<C_DIM;k++){
        const float qv = U.pre.qsL[pq][k];
        const float2 wo = *(const float2*)&Wo[k*64 + h*16 + pj*2];
        ao0 += qv*wo.x; ao1 += qv*wo.y;
        aa  += qv*Wa[k*32 + h*8 + pj];
      }
      const int q = c*32 + pq;
      offsL[q][pj*2]   = ao0;
      offsL[q][pj*2+1] = ao1;
      U.pre.logitsL[q][pj] = aa;
    }
    __syncthreads();
  }
  // ---- 2) softmax + mask flags (one thread per query) ----
  if(tid < 128){
    const int q = tid;
    const float* L = U.pre.logitsL[q];
    float mx = L[0];
    #pragma unroll
    for(int p=1;p<8;p++) mx = fmaxf(mx, L[p]);
    float e[8], ssum = 0.f;
    #pragma unroll
    for(int p=0;p<8;p++){ e[p] = __expf(L[p]-mx); ssum += e[p]; }
    const float inv = 1.f/ssum;
    #pragma unroll
    for(int p=0;p<8;p++) attnL[q][p] = e[p]*inv;
    int cnt = 0;
    #pragma unroll
    for(int s=0;s<S_CAM;s++){
      const bool a = mask_any(mask, mflag, ((size_t)s*N_Q + (n0+q))*D_Z);
      activL[q][s] = a ? 1 : 0;
      cnt += a ? 1 : 0;
    }
    cinvL[q] = 1.f / fmaxf((float)cnt, 1.f);
  }
  __syncthreads();                            // logits read done -> cam may overwrite

  // ---- 3) camera loop: stage slice to LDS, gather from LDS ----
  const int gq = tid >> 1, cg = tid & 1;      // query, 16-ch half of the head
  const int n  = n0 + gq;
  float acc[16];
  #pragma unroll
  for(int i=0;i<16;i++) acc[i]=0.f;

  for(int s=0;s<S_CAM;s++){
    #pragma unroll
    for(int i=0;i<6;i++){                     // 1400 rows, 256 threads
      const int r = i*256 + tid;
      if(r < M_VAL){
        const unsigned char* src = v8 + ((size_t)s*M_VAL + r)*C_DIM + h*32;
        const uint4 w0 = *(const uint4*)(src);
        const uint4 w1 = *(const uint4*)(src + 16);
        *(uint4*)&U.cam[r*CSTR]      = w0;
        *(uint4*)&U.cam[r*CSTR + 16] = w1;
      }
    }
    __syncthreads();
    {
      const float actf = activL[gq][s] ? 1.f : 0.f;
      const float2* refp = (const float2*)ref + ((size_t)s*N_Q + n)*D_Z;
      #pragma unroll 2
      for(int p=0;p<8;p++){                   // point p <-> z-anchor d=p
        const float2 r2 = refp[p];
        const float ox = offsL[gq][p*2+0];
        const float oy = offsL[gq][p*2+1];
        const float x = fmaf(r2.x, (float)WF, ox - 0.5f);
        const float y = fmaf(r2.y, (float)HF, oy - 0.5f);
        const float x0f = floorf(x), y0f = floorf(y);
        const float fx = x - x0f,    fy = y - y0f;
        const int x0 = (int)x0f, y0 = (int)y0f;
        const int x1 = x0+1,     y1 = y0+1;
        const float at = attnL[gq][p] * actf;
        const float wx0 = (x0>=0 && x0<WF) ? (1.f-fx) : 0.f;
        const float wx1 = (x1>=0 && x1<WF) ? fx       : 0.f;
        const float wy0 = ((y0>=0 && y0<HF) ? (1.f-fy) : 0.f) * at;
        const float wy1 = ((y1>=0 && y1<HF) ? fy       : 0.f) * at;
        const int x0c = min(max(x0,0), WF-1), x1c = min(max(x1,0), WF-1);
        const int y0c = min(max(y0,0), HF-1), y1c = min(max(y1,0), HF-1);
        const float w00 = wx0*wy0, w01 = wx1*wy0, w10 = wx0*wy1, w11 = wx1*wy1;
        const int co = cg*16;
        const uint4 c00 = *(const uint4*)&U.cam[(y0c*WF+x0c)*CSTR + co];
        const uint4 c01 = *(const uint4*)&U.cam[(y0c*WF+x1c)*CSTR + co];
        const uint4 c10 = *(const uint4*)&U.cam[(y1c*WF+x0c)*CSTR + co];
        const uint4 c11 = *(const uint4*)&U.cam[(y1c*WF+x1c)*CSTR + co];
        corner_acc(c00, w00, acc);
        corner_acc(c01, w01, acc);
        corner_acc(c10, w10, acc);
        corner_acc(c11, w11, acc);
      }
    }
    __syncthreads();                          // before next camera overwrites LDS
  }

  // ---- 4) slots (fp16) ----
  {
    const float inv = cinvL[gq];
    unsigned wds[8];
    #pragma unroll
    for(int j=0;j<8;j++){
      const unsigned lo = __half_as_ushort(__float2half_rn(acc[2*j+0]*inv));
      const unsigned hi = __half_as_ushort(__float2half_rn(acc[2*j+1]*inv));
      wds[j] = lo | (hi << 16);
    }
    unsigned short* dst = slots16 + (size_t)n*C_DIM + h*32 + cg*16;
    *(uint4*)(dst)     = make_uint4(wds[0], wds[1], wds[2], wds[3]);
    *(uint4*)(dst + 8) = make_uint4(wds[4], wds[5], wds[6], wds[7]);
  }
}

// ---------------------------------------------------------------------------
// C: out = slots @ Wout + bout + query (original-query residual), f32 out.
// 16 rows x 256 threads (proven shape).
// ---------------------------------------------------------------------------
__global__ __launch_bounds__(256)
void out_proj_kernel(const unsigned short* __restrict__ slots16,
                     const float* __restrict__ Wout,
                     const float* __restrict__ bout,
                     const float* __restrict__ query,
                     float* __restrict__ out){
  __shared__ float tile[16][C_DIM];
  const int tid = threadIdx.x;
  const int r0  = blockIdx.x * 16;
  {
    const int row = tid >> 4, seg = tid & 15;  // 16 rows x 16 uint4 segs
    const uint4 u = *(const uint4*)(slots16 + (size_t)(r0+row)*C_DIM + seg*8);
    const __half* hp = (const __half*)&u;
    #pragma unroll
    for(int j=0;j<8;j++) tile[row][seg*8+j] = __half2float(hp[j]);
  }
  __syncthreads();
  const int col = tid & 127;
  const int rh  = tid >> 7;
  float acc[8];
  const float bias = bout[col];
  #pragma unroll
  for(int r=0;r<8;r++) acc[r]=bias;
  for(int k=0;k<C_DIM;k+=4){
    const float w0 = Wout[(k+0)*C_DIM + col];
    const float w1 = Wout[(k+1)*C_DIM + col];
    const float w2 = Wout[(k+2)*C_DIM + col];
    const float w3 = Wout[(k+3)*C_DIM + col];
    #pragma unroll
    for(int r=0;r<8;r++){
      const float4 t = *(const float4*)&tile[rh*8+r][k];
      acc[r] += t.x*w0 + t.y*w1 + t.z*w2 + t.w*w3;
    }
  }
  #pragma unroll
  for(int r=0;r<8;r++){
    const size_t idx = (size_t)(r0+rh*8+r)*C_DIM + col;
    out[idx] = acc[r] + query[idx];
  }
}

extern "C" void kernel_launch(void* const* d_in, const int* in_sizes, int n_in,
                              void* d_out, int out_size, void* d_ws, size_t ws_size,
                              hipStream_t stream){
  const float* query     = (const float*)d_in[0];
  const float* query_pos = (const float*)d_in[1];
  const float* value     = (const float*)d_in[2];
  const float* ref       = (const float*)d_in[3];
  const unsigned char* mask = (const unsigned char*)d_in[4];
  const float* Wv   = (const float*)d_in[5];
  const float* bv   = (const float*)d_in[6];
  const float* Wo   = (const float*)d_in[7];
  const float* bo   = (const float*)d_in[8];
  const float* Wa   = (const float*)d_in[9];
  const float* ba   = (const float*)d_in[10];
  const float* Wout = (const float*)d_in[11];
  const float* bout = (const float*)d_in[12];
  float* out = (float*)d_out;

  // ws: [flag 64B][v8 fp8 1.05MB][slots fp16 4.2MB] ~= 5.3MB total
  int* flag = (int*)d_ws;
  unsigned char*  v8      = (unsigned char*)((char*)d_ws + 64);
  unsigned short* slots16 = (unsigned short*)((char*)d_ws + 64 + (size_t)S_CAM*M_VAL*C_DIM);

  value_proj_kernel<<<(S_CAM*M_VAL)/8, 256, 0, stream>>>(value, Wv, bv, v8, mask, flag);
  gather_kernel<<<(N_Q/QT)*4, 256, 0, stream>>>(v8, query, query_pos,
                                                Wo, bo, Wa, ba, ref, mask, flag, slots16);
  out_proj_kernel<<<N_Q/16, 256, 0, stream>>>(slots16, Wout, bout, query, out);
}

// Round 15
// 187.892 us; speedup vs baseline: 1.1797x; 1.1797x over previous
//
#include <hip/hip_runtime.h>

#define N_Q   16384
#define C_DIM 128
#define S_CAM 6
#define M_VAL 1400   // 28*50
#define D_Z   8
#define HF    28
#define WF    50
#define QPB   16     // queries per block; 16 lanes/query = (cam-half, 8x16ch)

typedef float f32x2 __attribute__((ext_vector_type(2)));

__device__ __forceinline__ bool mask_any(const unsigned char* __restrict__ mask,
                                         int mflag, size_t mbase){
  if(mflag==0){
    int any=0;
    #pragma unroll
    for(int d=0;d<D_Z;d++) any |= mask[mbase+d];
    return any!=0;
  } else if(mflag==1){
    const int* mp = (const int*)mask;  int any=0;
    #pragma unroll
    for(int d=0;d<D_Z;d++) any |= mp[mbase+d];
    return any!=0;
  } else {
    const long long* mp = (const long long*)mask;  long long any=0;
    #pragma unroll
    for(int d=0;d<D_Z;d++) any |= mp[mbase+d];
    return any!=0;
  }
}

// fp8x16 corner accumulate: 16 channels from one uint4, weight wgt.
__device__ __forceinline__ void corner_acc(const uint4 cv, const float wgt,
                                           float* __restrict__ acc){
  const unsigned dw[4] = {cv.x, cv.y, cv.z, cv.w};
  #pragma unroll
  for(int j=0;j<4;j++){
    const f32x2 lo = __builtin_amdgcn_cvt_pk_f32_fp8(dw[j], false);
    const f32x2 hi = __builtin_amdgcn_cvt_pk_f32_fp8(dw[j], true);
    acc[j*4+0] += wgt*lo[0];  acc[j*4+1] += wgt*lo[1];
    acc[j*4+2] += wgt*hi[0];  acc[j*4+3] += wgt*hi[1];
  }
}

// bilinear weights+addresses for one point (pure-register math).
__device__ __forceinline__ void point_setup(const float2 r2, const float ox,
                                            const float oy, const float at,
                                            int* __restrict__ idx,
                                            float* __restrict__ wgt){
  const float x = fmaf(r2.x, (float)WF, ox - 0.5f);
  const float y = fmaf(r2.y, (float)HF, oy - 0.5f);
  const float x0f = floorf(x), y0f = floorf(y);
  const float fx = x - x0f,    fy = y - y0f;
  const int x0 = (int)x0f, y0 = (int)y0f;
  const int x1 = x0+1,     y1 = y0+1;
  const float wx0 = (x0>=0 && x0<WF) ? (1.f-fx) : 0.f;
  const float wx1 = (x1>=0 && x1<WF) ? fx       : 0.f;
  const float wy0 = ((y0>=0 && y0<HF) ? (1.f-fy) : 0.f) * at;
  const float wy1 = ((y1>=0 && y1<HF) ? fy       : 0.f) * at;
  const int x0c = min(max(x0,0), WF-1), x1c = min(max(x1,0), WF-1);
  const int y0c = min(max(y0,0), HF-1), y1c = min(max(y1,0), HF-1);
  idx[0] = (y0c*WF+x0c)*C_DIM;  idx[1] = (y0c*WF+x1c)*C_DIM;
  idx[2] = (y1c*WF+x0c)*C_DIM;  idx[3] = (y1c*WF+x1c)*C_DIM;
  wgt[0] = wx0*wy0;  wgt[1] = wx1*wy0;  wgt[2] = wx0*wy1;  wgt[3] = wx1*wy1;
}

// ---------------------------------------------------------------------------
// v = value @ Wv + bv -> FP8 e4m3 workspace (proven R13 shape).
// Block 0 piggybacks the bev_mask upload-format sniff (0=u8,1=i32,2=i64).
// ---------------------------------------------------------------------------
__global__ __launch_bounds__(256)
void value_proj_kernel(const float* __restrict__ value,
                       const float* __restrict__ Wv,
                       const float* __restrict__ bv,
                       unsigned char* __restrict__ v8,
                       const unsigned char* __restrict__ mask,
                       int* __restrict__ flag){
  __shared__ float tile[8][C_DIM];
  __shared__ int s_cntA, s_cntB;
  const int tid = threadIdx.x;
  const int col = tid & 127;
  const int rh  = tid >> 7;
  const int r0  = blockIdx.x * 8;
  if(blockIdx.x==0 && tid==0){ s_cntA=0; s_cntB=0; }
  {
    const float4* src = (const float4*)(value + (size_t)r0*C_DIM);
    ((float4*)&tile[0][0])[tid] = src[tid];
  }
  __syncthreads();
  float acc[4];
  const float bias = bv[col];
  #pragma unroll
  for(int r=0;r<4;r++) acc[r]=bias;
  for(int k=0;k<C_DIM;k+=4){
    const float w0 = Wv[(k+0)*C_DIM + col];
    const float w1 = Wv[(k+1)*C_DIM + col];
    const float w2 = Wv[(k+2)*C_DIM + col];
    const float w3 = Wv[(k+3)*C_DIM + col];
    #pragma unroll
    for(int r=0;r<4;r++){
      const float4 t = *(const float4*)&tile[rh*4+r][k];
      acc[r] += t.x*w0 + t.y*w1 + t.z*w2 + t.w*w3;
    }
  }
  #pragma unroll
  for(int r=0;r<4;r++){
    const int pk = __builtin_amdgcn_cvt_pk_fp8_f32(acc[r], acc[r], 0, false);
    v8[(size_t)(r0+rh*4+r)*C_DIM + col] = (unsigned char)(pk & 0xff);
  }
  if(blockIdx.x==0){
    int a=0, b=0;
    for(int i=tid;i<1024;i+=256){
      const unsigned char v = mask[i];
      if(((i&3)!=0) && v) a=1;
      if(((i&7)==4) && v) b=1;
    }
    if(a) atomicOr(&s_cntA,1);
    if(b) atomicOr(&s_cntB,1);
    __syncthreads();
    if(tid==0) flag[0] = s_cntA ? 0 : (s_cntB ? 1 : 2);
  }
}

// ---------------------------------------------------------------------------
// Fused deformable attention, R15: chain-ILP gather. Per-lane offs/attns
// hoisted to REGISTERS before the cam loop (removes ~3 LDS round-trips from
// every point's dependency chain); per camera refs are register-prefetched;
// points processed in explicit PAIRS: both coord chains independent, all 8
// corner loads issued back-to-back, then FMAs (R10-R14 evidence: waves sit
// ~94% stalled on per-lane chains; occupancy/bytes changes were ~neutral).
// ---------------------------------------------------------------------------
__global__ __launch_bounds__(256)
void fused_deform_kernel(const unsigned char* __restrict__ v8,
                         const float* __restrict__ query,
                         const float* __restrict__ query_pos,
                         const float* __restrict__ Wo, const float* __restrict__ bo,
                         const float* __restrict__ Wa, const float* __restrict__ ba,
                         const float* __restrict__ ref,
                         const unsigned char* __restrict__ mask,
                         const int* __restrict__ flag,
                         const float* __restrict__ Wout,
                         const float* __restrict__ bout,
                         float* __restrict__ out){
  __shared__ float  qs[QPB][C_DIM+4];        // q staging; reused as slot partials
  __shared__ float  offs[QPB][68];
  __shared__ float  attns[QPB][36];
  __shared__ float  logits[QPB][36];
  __shared__ float2 refs[QPB][S_CAM*D_Z+1];
  __shared__ int    activ[QPB][S_CAM];
  __shared__ float  cinv[QPB];

  const int tid = threadIdx.x;
  const int n0  = blockIdx.x * QPB;
  const int mflag = flag[0];
  const int qi = tid >> 4;                   // query in block (0..15)
  const int l  = tid & 15;                   // lane within query group

  // ---- 0) ref prefetch (768 float2; 3/thread) ----
  float2 rpre[3];
  #pragma unroll
  for(int j=0;j<3;j++){
    const int e = tid + 256*j;               // e -> q=e/48, s=(e%48)/8, p=e%8
    const int q = e/48, r = e%48;
    rpre[j] = ((const float2*)ref)[((size_t)(r>>3)*N_Q + (n0+q))*D_Z + (r&7)];
  }

  // ---- 1) q = query + query_pos ----
  {
    const float4* qa = (const float4*)(query     + (size_t)n0*C_DIM);
    const float4* qb = (const float4*)(query_pos + (size_t)n0*C_DIM);
    #pragma unroll
    for(int j=0;j<2;j++){
      const int idx = tid + 256*j;
      const int r = idx >> 5, c4 = idx & 31;
      float4 A = qa[idx], B = qb[idx];
      *(float4*)&qs[r][c4*4] = make_float4(A.x+B.x, A.y+B.y, A.z+B.z, A.w+B.w);
    }
  }
  __syncthreads();

  // ---- 2) projections: lane l -> off cols l*4.., logit cols l*2.. ----
  {
    float ao0 = bo[l*4+0], ao1 = bo[l*4+1], ao2 = bo[l*4+2], ao3 = bo[l*4+3];
    float aa0 = ba[l*2+0], aa1 = ba[l*2+1];
    for(int k=0;k<C_DIM;k++){
      const float qv = qs[qi][k];
      const float4 wo = *(const float4*)&Wo[k*64 + l*4];
      const float2 wa = *(const float2*)&Wa[k*32 + l*2];
      ao0 += qv*wo.x; ao1 += qv*wo.y; ao2 += qv*wo.z; ao3 += qv*wo.w;
      aa0 += qv*wa.x; aa1 += qv*wa.y;
    }
    offs[qi][l*4+0] = ao0;  offs[qi][l*4+1] = ao1;
    offs[qi][l*4+2] = ao2;  offs[qi][l*4+3] = ao3;
    logits[qi][l*2+0] = aa0;  logits[qi][l*2+1] = aa1;
  }
  #pragma unroll
  for(int j=0;j<3;j++){
    const int e = tid + 256*j;
    refs[e/48][e%48] = rpre[j];
  }
  if(tid < QPB*S_CAM){
    const int q2 = tid / S_CAM, s = tid % S_CAM;
    activ[q2][s] = mask_any(mask, mflag, ((size_t)s*N_Q + (n0+q2))*D_Z) ? 1 : 0;
  }
  __syncthreads();
  if(tid < 64){                              // softmax over P=8: (q2, h)
    const int q2 = tid >> 2, h = tid & 3;
    const float* L = &logits[q2][h*8];
    float mx = L[0];
    #pragma unroll
    for(int p=1;p<8;p++) mx = fmaxf(mx, L[p]);
    float e[8], ssum = 0.f;
    #pragma unroll
    for(int p=0;p<8;p++){ e[p] = __expf(L[p]-mx); ssum += e[p]; }
    const float inv = 1.f/ssum;
    #pragma unroll
    for(int p=0;p<8;p++) attns[q2][h*8+p] = e[p]*inv;
  } else if(tid >= 256-QPB){
    const int q2 = tid - (256-QPB);
    int c = 0;
    #pragma unroll
    for(int s=0;s<S_CAM;s++) c += activ[q2][s];
    cinv[q2] = 1.f / fmaxf((float)c, 1.f);
  }
  __syncthreads();

  // ---- 3) gather: lane = (sg cam-half, 16ch); reg-hoisted state ----
  const int sg  = l >> 3;                    // cams sg*3 .. sg*3+2
  const int ll  = l & 7;                     // 16-ch group
  const int gch = ll*16;
  const int gh  = ll >> 1;                   // head (32 ch/head)

  // hoist: this head's 16 offsets + 8 attn weights into registers
  float oxr[8], oyr[8], atr[8];
  #pragma unroll
  for(int p=0;p<8;p++){
    oxr[p] = offs[qi][gh*16+p*2+0];
    oyr[p] = offs[qi][gh*16+p*2+1];
    atr[p] = attns[qi][gh*8+p];
  }

  float acc[16];
  #pragma unroll
  for(int i=0;i<16;i++) acc[i]=0.f;

  for(int s=sg*3; s<sg*3+3; s++){
    if(!activ[qi][s]) continue;
    const unsigned char* vb = v8 + (size_t)s*M_VAL*C_DIM + gch;
    // prefetch this cam's 8 refs into registers
    float2 rr[8];
    #pragma unroll
    for(int p=0;p<8;p++) rr[p] = refs[qi][s*8+p];
    // 4 pairs of points: two independent coord chains, 8 loads in flight
    #pragma unroll
    for(int pp=0;pp<4;pp++){
      const int p0 = pp*2, p1 = pp*2+1;
      int   idxA[4], idxB[4];
      float wgtA[4], wgtB[4];
      point_setup(rr[p0], oxr[p0], oyr[p0], atr[p0], idxA, wgtA);
      point_setup(rr[p1], oxr[p1], oyr[p1], atr[p1], idxB, wgtB);
      const uint4 a0 = *(const uint4*)(vb + idxA[0]);
      const uint4 a1 = *(const uint4*)(vb + idxA[1]);
      const uint4 a2 = *(const uint4*)(vb + idxA[2]);
      const uint4 a3 = *(const uint4*)(vb + idxA[3]);
      const uint4 b0 = *(const uint4*)(vb + idxB[0]);
      const uint4 b1 = *(const uint4*)(vb + idxB[1]);
      const uint4 b2 = *(const uint4*)(vb + idxB[2]);
      const uint4 b3 = *(const uint4*)(vb + idxB[3]);
      corner_acc(a0, wgtA[0], acc);
      corner_acc(a1, wgtA[1], acc);
      corner_acc(a2, wgtA[2], acc);
      corner_acc(a3, wgtA[3], acc);
      corner_acc(b0, wgtB[0], acc);
      corner_acc(b1, wgtB[1], acc);
      corner_acc(b2, wgtB[2], acc);
      corner_acc(b3, wgtB[3], acc);
    }
  }

  // ---- 4) merge cam-half partials in qs, then out-proj + residual ----
  __syncthreads();                           // all phase-2 qs reads complete
  if(sg==0){
    #pragma unroll
    for(int i=0;i<4;i++)
      *(float4*)&qs[qi][gch+i*4] = *(const float4*)&acc[i*4];
  }
  __syncthreads();
  if(sg==1){
    const float inv = cinv[qi];
    #pragma unroll
    for(int i=0;i<4;i++){
      float4 pA = *(const float4*)&qs[qi][gch+i*4];
      *(float4*)&qs[qi][gch+i*4] = make_float4((pA.x+acc[i*4+0])*inv,
                                               (pA.y+acc[i*4+1])*inv,
                                               (pA.z+acc[i*4+2])*inv,
                                               (pA.w+acc[i*4+3])*inv);
    }
  }
  __syncthreads();
  {
    const int c0 = l*8;                      // 8 output cols per lane
    const int n  = n0 + qi;
    const float4 bA = *(const float4*)&bout[c0];
    const float4 bB = *(const float4*)&bout[c0+4];
    const float4 rA = *(const float4*)&query[(size_t)n*C_DIM + c0];
    const float4 rB = *(const float4*)&query[(size_t)n*C_DIM + c0 + 4];
    float o0=bA.x+rA.x, o1=bA.y+rA.y, o2=bA.z+rA.z, o3=bA.w+rA.w;
    float o4=bB.x+rB.x, o5=bB.y+rB.y, o6=bB.z+rB.z, o7=bB.w+rB.w;
    for(int k=0;k<C_DIM;k++){
      const float sv = qs[qi][k];
      const float4 wA = *(const float4*)&Wout[(size_t)k*C_DIM + c0];
      const float4 wB = *(const float4*)&Wout[(size_t)k*C_DIM + c0 + 4];
      o0 += sv*wA.x; o1 += sv*wA.y; o2 += sv*wA.z; o3 += sv*wA.w;
      o4 += sv*wB.x; o5 += sv*wB.y; o6 += sv*wB.z; o7 += sv*wB.w;
    }
    *(float4*)&out[(size_t)n*C_DIM + c0]     = make_float4(o0,o1,o2,o3);
    *(float4*)&out[(size_t)n*C_DIM + c0 + 4] = make_float4(o4,o5,o6,o7);
  }
}

extern "C" void kernel_launch(void* const* d_in, const int* in_sizes, int n_in,
                              void* d_out, int out_size, void* d_ws, size_t ws_size,
                              hipStream_t stream){
  const float* query     = (const float*)d_in[0];
  const float* query_pos = (const float*)d_in[1];
  const float* value     = (const float*)d_in[2];
  const float* ref       = (const float*)d_in[3];
  const unsigned char* mask = (const unsigned char*)d_in[4];
  const float* Wv   = (const float*)d_in[5];
  const float* bv   = (const float*)d_in[6];
  const float* Wo   = (const float*)d_in[7];
  const float* bo   = (const float*)d_in[8];
  const float* Wa   = (const float*)d_in[9];
  const float* ba   = (const float*)d_in[10];
  const float* Wout = (const float*)d_in[11];
  const float* bout = (const float*)d_in[12];
  float* out = (float*)d_out;

  int* flag = (int*)d_ws;
  unsigned char* v8 = (unsigned char*)((char*)d_ws + 64);

  value_proj_kernel<<<(S_CAM*M_VAL)/8, 256, 0, stream>>>(value, Wv, bv, v8, mask, flag);
  fused_deform_kernel<<<N_Q/QPB, 256, 0, stream>>>(v8, query, query_pos,
                                                   Wo, bo, Wa, ba, ref, mask, flag,
                                                   Wout, bout, out);
}

// Round 19
// 186.983 us; speedup vs baseline: 1.1854x; 1.0049x over previous
//
#include <hip/hip_runtime.h>

#define N_Q   16384
#define C_DIM 128
#define S_CAM 6
#define M_VAL 1400   // 28*50
#define D_Z   8
#define HF    28
#define WF    50
#define QPB   16     // queries per block; 16 lanes/query = (cam-half, 8x16ch)

typedef float f32x2 __attribute__((ext_vector_type(2)));

__device__ __forceinline__ bool mask_any(const unsigned char* __restrict__ mask,
                                         int mflag, size_t mbase){
  if(mflag==0){
    int any=0;
    #pragma unroll
    for(int d=0;d<D_Z;d++) any |= mask[mbase+d];
    return any!=0;
  } else if(mflag==1){
    const int* mp = (const int*)mask;  int any=0;
    #pragma unroll
    for(int d=0;d<D_Z;d++) any |= mp[mbase+d];
    return any!=0;
  } else {
    const long long* mp = (const long long*)mask;  long long any=0;
    #pragma unroll
    for(int d=0;d<D_Z;d++) any |= mp[mbase+d];
    return any!=0;
  }
}

// fp8x16 corner accumulate: 16 channels from one uint4, weight wgt.
__device__ __forceinline__ void corner_acc(const uint4 cv, const float wgt,
                                           float* __restrict__ acc){
  const unsigned dw[4] = {cv.x, cv.y, cv.z, cv.w};
  #pragma unroll
  for(int j=0;j<4;j++){
    const f32x2 lo = __builtin_amdgcn_cvt_pk_f32_fp8(dw[j], false);
    const f32x2 hi = __builtin_amdgcn_cvt_pk_f32_fp8(dw[j], true);
    acc[j*4+0] += wgt*lo[0];  acc[j*4+1] += wgt*lo[1];
    acc[j*4+2] += wgt*hi[0];  acc[j*4+3] += wgt*hi[1];
  }
}

// ---------------------------------------------------------------------------
// v = value @ Wv + bv (8400x128 @ 128x128) -> FP8 e4m3 workspace (HW cvt;
// same HW format encode+decode -> self-consistent roundtrip).
// Block 0 piggybacks the bev_mask upload-format sniff (0=u8,1=i32,2=i64).
// ---------------------------------------------------------------------------
__global__ __launch_bounds__(256)
void value_proj_kernel(const float* __restrict__ value,
                       const float* __restrict__ Wv,
                       const float* __restrict__ bv,
                       unsigned char* __restrict__ v8,
                       const unsigned char* __restrict__ mask,
                       int* __restrict__ flag){
  __shared__ float tile[8][C_DIM];
  __shared__ int s_cntA, s_cntB;
  const int tid = threadIdx.x;
  const int col = tid & 127;
  const int rh  = tid >> 7;                    // rows rh*4 .. rh*4+3
  const int r0  = blockIdx.x * 8;
  if(blockIdx.x==0 && tid==0){ s_cntA=0; s_cntB=0; }
  {
    const float4* src = (const float4*)(value + (size_t)r0*C_DIM);
    ((float4*)&tile[0][0])[tid] = src[tid];
  }
  __syncthreads();
  float acc[4];
  const float bias = bv[col];
  #pragma unroll
  for(int r=0;r<4;r++) acc[r]=bias;
  for(int k=0;k<C_DIM;k+=4){
    const float w0 = Wv[(k+0)*C_DIM + col];
    const float w1 = Wv[(k+1)*C_DIM + col];
    const float w2 = Wv[(k+2)*C_DIM + col];
    const float w3 = Wv[(k+3)*C_DIM + col];
    #pragma unroll
    for(int r=0;r<4;r++){
      const float4 t = *(const float4*)&tile[rh*4+r][k];
      acc[r] += t.x*w0 + t.y*w1 + t.z*w2 + t.w*w3;
    }
  }
  #pragma unroll
  for(int r=0;r<4;r++){
    const int pk = __builtin_amdgcn_cvt_pk_fp8_f32(acc[r], acc[r], 0, false);
    v8[(size_t)(r0+rh*4+r)*C_DIM + col] = (unsigned char)(pk & 0xff);
  }
  if(blockIdx.x==0){
    int a=0, b=0;
    for(int i=tid;i<1024;i+=256){
      const unsigned char v = mask[i];
      if(((i&3)!=0) && v) a=1;
      if(((i&7)==4) && v) b=1;
    }
    if(a) atomicOr(&s_cntA,1);
    if(b) atomicOr(&s_cntB,1);
    __syncthreads();
    if(tid==0) flag[0] = s_cntA ? 0 : (s_cntB ? 1 : 2);
  }
}

// ---------------------------------------------------------------------------
// Fused deformable attention. 16 lanes/query: lane = (cam-half sg, 16-ch
// group). FP8 gather: one 16B load = 16 channels. Decode 2 fp8 -> 2 f32 per
// v_cvt_pk_f32_fp8, f32 accumulate. Barrier-free gather; partials merged
// via LDS RMW. __launch_bounds__(256) only (every forced cap spilled).
// ---------------------------------------------------------------------------
__global__ __launch_bounds__(256)
void fused_deform_kernel(const unsigned char* __restrict__ v8,
                         const float* __restrict__ query,
                         const float* __restrict__ query_pos,
                         const float* __restrict__ Wo, const float* __restrict__ bo,
                         const float* __restrict__ Wa, const float* __restrict__ ba,
                         const float* __restrict__ ref,
                         const unsigned char* __restrict__ mask,
                         const int* __restrict__ flag,
                         const float* __restrict__ Wout,
                         const float* __restrict__ bout,
                         float* __restrict__ out){
  __shared__ float  qs[QPB][C_DIM+4];        // q staging; reused as slot partials
  __shared__ float  offs[QPB][68];           // 68 mod 32 = 4
  __shared__ float  attns[QPB][36];
  __shared__ float  logits[QPB][36];
  __shared__ float2 refs[QPB][S_CAM*D_Z+1];  // 49 f2 rows: 98 mod 32 = 2
  __shared__ int    activ[QPB][S_CAM];
  __shared__ float  cinv[QPB];

  const int tid = threadIdx.x;
  const int n0  = blockIdx.x * QPB;
  const int mflag = flag[0];
  const int qi = tid >> 4;                   // query in block (0..15)
  const int l  = tid & 15;                   // lane within query group

  // ---- 0) ref prefetch (768 float2; 3/thread) ----
  float2 rpre[3];
  #pragma unroll
  for(int j=0;j<3;j++){
    const int e = tid + 256*j;               // e -> q=e/48, s=(e%48)/8, p=e%8
    const int q = e/48, r = e%48;
    rpre[j] = ((const float2*)ref)[((size_t)(r>>3)*N_Q + (n0+q))*D_Z + (r&7)];
  }

  // ---- 1) q = query + query_pos ----
  {
    const float4* qa = (const float4*)(query     + (size_t)n0*C_DIM);
    const float4* qb = (const float4*)(query_pos + (size_t)n0*C_DIM);
    #pragma unroll
    for(int j=0;j<2;j++){
      const int idx = tid + 256*j;
      const int r = idx >> 5, c4 = idx & 31;
      float4 A = qa[idx], B = qb[idx];
      *(float4*)&qs[r][c4*4] = make_float4(A.x+B.x, A.y+B.y, A.z+B.z, A.w+B.w);
    }
  }
  __syncthreads();

  // ---- 2) projections: lane l -> off cols l*4.., logit cols l*2.. ----
  {
    float ao0 = bo[l*4+0], ao1 = bo[l*4+1], ao2 = bo[l*4+2], ao3 = bo[l*4+3];
    float aa0 = ba[l*2+0], aa1 = ba[l*2+1];
    for(int k=0;k<C_DIM;k++){
      const float qv = qs[qi][k];
      const float4 wo = *(const float4*)&Wo[k*64 + l*4];
      const float2 wa = *(const float2*)&Wa[k*32 + l*2];
      ao0 += qv*wo.x; ao1 += qv*wo.y; ao2 += qv*wo.z; ao3 += qv*wo.w;
      aa0 += qv*wa.x; aa1 += qv*wa.y;
    }
    offs[qi][l*4+0] = ao0;  offs[qi][l*4+1] = ao1;
    offs[qi][l*4+2] = ao2;  offs[qi][l*4+3] = ao3;
    logits[qi][l*2+0] = aa0;  logits[qi][l*2+1] = aa1;
  }
  #pragma unroll
  for(int j=0;j<3;j++){
    const int e = tid + 256*j;
    refs[e/48][e%48] = rpre[j];
  }
  if(tid < QPB*S_CAM){
    const int q2 = tid / S_CAM, s = tid % S_CAM;
    activ[q2][s] = mask_any(mask, mflag, ((size_t)s*N_Q + (n0+q2))*D_Z) ? 1 : 0;
  }
  __syncthreads();
  if(tid < 64){                              // softmax over P=8: (q2, h)
    const int q2 = tid >> 2, h = tid & 3;
    const float* L = &logits[q2][h*8];
    float mx = L[0];
    #pragma unroll
    for(int p=1;p<8;p++) mx = fmaxf(mx, L[p]);
    float e[8], ssum = 0.f;
    #pragma unroll
    for(int p=0;p<8;p++){ e[p] = __expf(L[p]-mx); ssum += e[p]; }
    const float inv = 1.f/ssum;
    #pragma unroll
    for(int p=0;p<8;p++) attns[q2][h*8+p] = e[p]*inv;
  } else if(tid >= 256-QPB){
    const int q2 = tid - (256-QPB);
    int c = 0;
    #pragma unroll
    for(int s=0;s<S_CAM;s++) c += activ[q2][s];
    cinv[q2] = 1.f / fmaxf((float)c, 1.f);
  }
  __syncthreads();

  // ---- 3) barrier-free FP8 gather: lane = (sg cam-half, 16ch), 3 cams ----
  const int sg  = l >> 3;                    // cams sg*3 .. sg*3+2
  const int ll  = l & 7;                     // 16-ch group
  const int gch = ll*16;                     // first channel
  const int gh  = ll >> 1;                   // head (32 ch/head)
  float acc[16];
  #pragma unroll
  for(int i=0;i<16;i++) acc[i]=0.f;

  for(int s=sg*3; s<sg*3+3; s++){
    if(!activ[qi][s]) continue;
    const unsigned char* vb = v8 + (size_t)s*M_VAL*C_DIM + gch;
    #pragma unroll 2
    for(int p=0;p<8;p++){                    // point p <-> z-anchor d=p (P//D==1)
      const float2 r2 = refs[qi][s*8+p];
      const float ox = offs[qi][gh*16+p*2+0];
      const float oy = offs[qi][gh*16+p*2+1];
      const float x = fmaf(r2.x, (float)WF, ox - 0.5f);
      const float y = fmaf(r2.y, (float)HF, oy - 0.5f);
      const float x0f = floorf(x), y0f = floorf(y);
      const float fx = x - x0f,    fy = y - y0f;
      const int x0 = (int)x0f, y0 = (int)y0f;
      const int x1 = x0+1,     y1 = y0+1;
      const float at = attns[qi][gh*8+p];
      const float wx0 = (x0>=0 && x0<WF) ? (1.f-fx) : 0.f;
      const float wx1 = (x1>=0 && x1<WF) ? fx       : 0.f;
      const float wy0 = ((y0>=0 && y0<HF) ? (1.f-fy) : 0.f) * at;
      const float wy1 = ((y1>=0 && y1<HF) ? fy       : 0.f) * at;
      const int x0c = min(max(x0,0), WF-1), x1c = min(max(x1,0), WF-1);
      const int y0c = min(max(y0,0), HF-1), y1c = min(max(y1,0), HF-1);
      const float w00 = wx0*wy0, w01 = wx1*wy0, w10 = wx0*wy1, w11 = wx1*wy1;
      const uint4 c00 = *(const uint4*)(vb + (size_t)(y0c*WF+x0c)*C_DIM);
      const uint4 c01 = *(const uint4*)(vb + (size_t)(y0c*WF+x1c)*C_DIM);
      const uint4 c10 = *(const uint4*)(vb + (size_t)(y1c*WF+x0c)*C_DIM);
      const uint4 c11 = *(const uint4*)(vb + (size_t)(y1c*WF+x1c)*C_DIM);
      corner_acc(c00, w00, acc);
      corner_acc(c01, w01, acc);
      corner_acc(c10, w10, acc);
      corner_acc(c11, w11, acc);
    }
  }

  // ---- 4) merge cam-half partials in qs, then out-proj + residual ----
  __syncthreads();                           // all phase-2 qs reads complete
  if(sg==0){
    #pragma unroll
    for(int i=0;i<4;i++)
      *(float4*)&qs[qi][gch+i*4] = *(const float4*)&acc[i*4];
  }
  __syncthreads();
  if(sg==1){
    const float inv = cinv[qi];
    #pragma unroll
    for(int i=0;i<4;i++){
      float4 pA = *(const float4*)&qs[qi][gch+i*4];
      *(float4*)&qs[qi][gch+i*4] = make_float4((pA.x+acc[i*4+0])*inv,
                                               (pA.y+acc[i*4+1])*inv,
                                               (pA.z+acc[i*4+2])*inv,
                                               (pA.w+acc[i*4+3])*inv);
    }
  }
  __syncthreads();
  {
    const int c0 = l*8;                      // 8 output cols per lane
    const int n  = n0 + qi;
    const float4 bA = *(const float4*)&bout[c0];
    const float4 bB = *(const float4*)&bout[c0+4];
    const float4 rA = *(const float4*)&query[(size_t)n*C_DIM + c0];
    const float4 rB = *(const float4*)&query[(size_t)n*C_DIM + c0 + 4];
    float o0=bA.x+rA.x, o1=bA.y+rA.y, o2=bA.z+rA.z, o3=bA.w+rA.w;
    float o4=bB.x+rB.x, o5=bB.y+rB.y, o6=bB.z+rB.z, o7=bB.w+rB.w;
    for(int k=0;k<C_DIM;k++){
      const float sv = qs[qi][k];
      const float4 wA = *(const float4*)&Wout[(size_t)k*C_DIM + c0];
      const float4 wB = *(const float4*)&Wout[(size_t)k*C_DIM + c0 + 4];
      o0 += sv*wA.x; o1 += sv*wA.y; o2 += sv*wA.z; o3 += sv*wA.w;
      o4 += sv*wB.x; o5 += sv*wB.y; o6 += sv*wB.z; o7 += sv*wB.w;
    }
    *(float4*)&out[(size_t)n*C_DIM + c0]     = make_float4(o0,o1,o2,o3);
    *(float4*)&out[(size_t)n*C_DIM + c0 + 4] = make_float4(o4,o5,o6,o7);
  }
}

extern "C" void kernel_launch(void* const* d_in, const int* in_sizes, int n_in,
                              void* d_out, int out_size, void* d_ws, size_t ws_size,
                              hipStream_t stream){
  const float* query     = (const float*)d_in[0];
  const float* query_pos = (const float*)d_in[1];
  const float* value     = (const float*)d_in[2];
  const float* ref       = (const float*)d_in[3];
  const unsigned char* mask = (const unsigned char*)d_in[4];
  const float* Wv   = (const float*)d_in[5];
  const float* bv   = (const float*)d_in[6];
  const float* Wo   = (const float*)d_in[7];
  const float* bo   = (const float*)d_in[8];
  const float* Wa   = (const float*)d_in[9];
  const float* ba   = (const float*)d_in[10];
  const float* Wout = (const float*)d_in[11];
  const float* bout = (const float*)d_in[12];
  float* out = (float*)d_out;

  int* flag = (int*)d_ws;
  unsigned char* v8 = (unsigned char*)((char*)d_ws + 64);

  value_proj_kernel<<<(S_CAM*M_VAL)/8, 256, 0, stream>>>(value, Wv, bv, v8, mask, flag);
  fused_deform_kernel<<<N_Q/QPB, 256, 0, stream>>>(v8, query, query_pos,
                                                   Wo, bo, Wa, ba, ref, mask, flag,
                                                   Wout, bout, out);
}